// Round 5
// baseline (125.166 us; speedup 1.0000x reference)
//
#include <hip/hip_runtime.h>

// Morphological dilation: out[p,i,j] = max_{r,c}(xpad[p,i+r,j+c] + w[p,r,c]) + bias[p]
// p = plane (B*C=1024), H=W=128, 5x5, pad=2, stride=1, fp32. Zero pad participates.
// R4 (resubmit — prior round hit GPUAcquisitionTimeout, never measured):
// one persistent block per plane; 4 sub-tiles of 32 rows double-buffered in LDS
// (T3 2-phase recipe): issue async global_load_lds for tile t+1 BEFORE computing
// tile t, one barrier per tile. Compute = 2 ds_read_b128 per row-advance, no
// bounds logic (zero-padded 36x132 tile).

static constexpr int H = 128, W = 128, KH = 5, KW = 5, PAD = 2;
static constexpr int TROWS = 32;             // output rows per sub-tile
static constexpr int PROWS = TROWS + KH - 1; // 36 padded rows
static constexpr int PCOLS = W + 2 * PAD;    // 132 padded cols
static constexpr int NT    = H / TROWS;      // 4 sub-tiles per plane

#define MAX3(a, b, c) fmaxf(fmaxf((a), (b)), (c))

__device__ inline void gload_lds4(const float* g, float* l) {
    __builtin_amdgcn_global_load_lds(
        (const __attribute__((address_space(1))) void*)g,
        (__attribute__((address_space(3))) void*)l, 4, 0, 0);
}

__global__ __launch_bounds__(256) void dilation_kernel(
    const float* __restrict__ x,
    const float* __restrict__ wgt,
    const float* __restrict__ bias,
    float* __restrict__ out)
{
    __shared__ float tile[2][PROWS * PCOLS]; // 2 x 19008 B = 38016 B

    const int plane = blockIdx.x;
    const int tid   = threadIdx.x;
    const int wave  = tid >> 6;
    const int lane  = tid & 63;

    const float* __restrict__ xp = x   + (size_t)plane * (H * W);
    float*       __restrict__ op = out + (size_t)plane * (H * W);
    const float* __restrict__ wp = wgt + plane * (KH * KW);

    // Stage sub-tile T's in-image rows into buffer BUF (interior cols only).
    // LDS dest is wave-uniform base + lane*4 (global_load_lds requirement).
#define STAGE(BUF, T)                                                         \
    do {                                                                      \
        const int r0_ = (T) * TROWS - PAD;                                    \
        _Pragma("unroll")                                                     \
        for (int chunk = 0; chunk < 2 * PROWS; chunk += 4) {                  \
            const int ch   = chunk + wave;  /* wave-uniform */                \
            const int pr   = ch >> 1;                                         \
            const int half = (ch & 1) * 64;                                   \
            const int irow = r0_ + pr;                                        \
            if (irow >= 0 && irow < H)                                        \
                gload_lds4(xp + irow * W + half + lane,                       \
                           &tile[BUF][pr * PCOLS + PAD + half]);              \
        }                                                                     \
    } while (0)

    // Prologue: issue stage of tile 0 first so loads fly during setup.
    STAGE(0, 0);

    // One-time zero of column pads (cols 0,1,130,131) of BOTH buffers —
    // staging never writes them, compute never overwrites them.
    if (tid < 144) {
        const int b  = tid / 72;
        const int r2 = tid % 72;
        const int r  = r2 >> 1;
        const int off = (r2 & 1) ? (PCOLS - 2) : 0;
        tile[b][r * PCOLS + off]     = 0.0f;
        tile[b][r * PCOLS + off + 1] = 0.0f;
    }
    // Tile 0 top halo (input rows -2,-1) = buf0 rows 0,1:
    if (tid < PCOLS) {
        tile[0][tid]         = 0.0f;
        tile[0][PCOLS + tid] = 0.0f;
    }

    // Plane-uniform weights -> SGPRs; bias applied last (exact ref op order).
    float wk[KH * KW];
#pragma unroll
    for (int i = 0; i < KH * KW; ++i) wk[i] = wp[i];
    const float bi = bias[plane];

    const int cg = tid & 31;   // 32 column groups x 4 cols
    const int rs = tid >> 5;   // 8 row streams x 4 rows
    const int j0 = cg * 4;
    const int tb = rs * 4;     // local output row base

    __syncthreads();           // buf0 staged (vmcnt+lgkm drained)

#pragma unroll
    for (int t = 0; t < NT; ++t) {
        const int cur = t & 1;

        // Issue next tile's stage BEFORE this tile's compute (T3 recipe).
        if (t < NT - 1) STAGE(cur ^ 1, t + 1);
        // Tile 3 bottom halo (input rows 128,129) = buf1 rows 34,35; written
        // during t==2 (buf1's rows 34,35 were last read in t==1's compute).
        if (t == 2 && tid < PCOLS) {
            tile[1][(PROWS - 2) * PCOLS + tid] = 0.0f;
            tile[1][(PROWS - 1) * PCOLS + tid] = 0.0f;
        }

        const float* __restrict__ tp = tile[cur];

        // Sliding 5-row register window of 8 padded cols (j0..j0+7).
        float win[KH][8];
#define LOAD_TROW(SLOT, PR)                                                   \
        do {                                                                  \
            const float* rp_ = tp + (PR) * PCOLS + j0;                        \
            const float4 a_ = *reinterpret_cast<const float4*>(rp_);          \
            const float4 b_ = *reinterpret_cast<const float4*>(rp_ + 4);      \
            win[SLOT][0] = a_.x; win[SLOT][1] = a_.y;                         \
            win[SLOT][2] = a_.z; win[SLOT][3] = a_.w;                         \
            win[SLOT][4] = b_.x; win[SLOT][5] = b_.y;                         \
            win[SLOT][6] = b_.z; win[SLOT][7] = b_.w;                         \
        } while (0)

#pragma unroll
        for (int pt = 0; pt < KH - 1; ++pt)
            LOAD_TROW(pt, tb + pt);

#pragma unroll
        for (int it = 0; it < 4; ++it) {
            LOAD_TROW((it + KH - 1) % KH, tb + it + KH - 1);

            float res[4];
#pragma unroll
            for (int k = 0; k < 4; ++k) {
                float v[KH * KW];
#pragma unroll
                for (int r = 0; r < KH; ++r) {
                    const int s = (it + r) % KH;
#pragma unroll
                    for (int c = 0; c < KW; ++c)
                        v[r * KW + c] = win[s][k + c] + wk[r * KW + c];
                }
                const float u0 = MAX3(v[0],  v[1],  v[2]);
                const float u1 = MAX3(v[3],  v[4],  v[5]);
                const float u2 = MAX3(v[6],  v[7],  v[8]);
                const float u3 = MAX3(v[9],  v[10], v[11]);
                const float u4 = MAX3(v[12], v[13], v[14]);
                const float u5 = MAX3(v[15], v[16], v[17]);
                const float u6 = MAX3(v[18], v[19], v[20]);
                const float u7 = MAX3(v[21], v[22], v[23]);
                const float w0 = MAX3(u0, u1, u2);
                const float w1 = MAX3(u3, u4, u5);
                const float w2 = MAX3(u6, u7, v[24]);
                res[k] = MAX3(w0, w1, w2) + bi;
            }

            float4 o;
            o.x = res[0]; o.y = res[1]; o.z = res[2]; o.w = res[3];
            const int grow = t * TROWS + tb + it;
            *reinterpret_cast<float4*>(op + grow * W + j0) = o;
        }
#undef LOAD_TROW

        __syncthreads();       // drains stage of t+1 (had whole compute to land)
    }
#undef STAGE
}

extern "C" void kernel_launch(void* const* d_in, const int* in_sizes, int n_in,
                              void* d_out, int out_size, void* d_ws, size_t ws_size,
                              hipStream_t stream) {
    const float* x    = (const float*)d_in[0];
    const float* wgt  = (const float*)d_in[1];
    const float* bias = (const float*)d_in[2];
    float* out        = (float*)d_out;

    const int planes = in_sizes[2];          // B*C = 1024
    dim3 grid(planes);                       // one block per plane
    dim3 block(256);                         // 4 waves
    dilation_kernel<<<grid, block, 0, stream>>>(x, wgt, bias, out);
}